// Round 5
// baseline (209.738 us; speedup 1.0000x reference)
//
#include <hip/hip_runtime.h>
#include <math.h>

#define NPIXD 1024
#define GD    2048
#define NCHAND 4
#define NVISD 200000
#define JW    6
#define KXROWS 408     // kx rows computed/stored (gather needs <=400; clamped)
#define YPACK  832     // packed y: pos=[0..415] <- y 0..415 ; pos=[416..831] <- y 1632..2047
#define RP     408     // R row pitch (float2), rows 64B-aligned (408*8=3264=51*64)
#define FINP   1024    // Fin row pitch (float2)
#define TWN    1536
#define IDX(i) ((i) + ((i) >> 4))   // LDS pad: kills 8-way bank conflicts at m=1,4

static constexpr double PI_D = 3.14159265358979323846;
static constexpr float SCALE_F = (float)(1000.0 * 0.005 * PI_D / (180.0 * 3600.0) * 2048.0);
static constexpr float BETA_F  = (float)(2.34 * 6.0);

// ---------------- apodization table ----------------
__global__ void apod_kernel(float* __restrict__ apod) {
    int i = blockIdx.x * 256 + threadIdx.x;
    if (i >= NPIXD) return;
    float n  = (float)(i - NPIXD / 2) / (float)GD;
    float t  = (float)(PI_D * (double)JW) * n;
    float arg = BETA_F * BETA_F - t * t;
    float sq  = sqrtf(fabsf(arg));
    float ft  = (arg > 0.0f) ? (sinhf(sq) / sq)
                             : ((sq == 0.0f) ? 1.0f : (sinf(sq) / sq));
    apod[i] = 1.0f / ft;
}

// ---------------- twiddle table: tw[t] = exp(-i*pi*t/1024), t in [0,1536) ----------------
__global__ void twiddle_kernel(float2* __restrict__ tw) {
    int t = blockIdx.x * 256 + threadIdx.x;
    if (t >= TWN) return;
    double ang = -PI_D * (double)t / 1024.0;
    tw[t] = make_float2((float)cos(ang), (float)sin(ang));
}

__device__ __forceinline__ float2 cmulf(float2 a, float2 b) {
    return make_float2(a.x * b.x - a.y * b.y, a.x * b.y + a.y * b.x);
}

// ---------------- 2048-pt Stockham FFT in LDS: 5x radix-4 + 1x radix-2 ----------------
// Derived by composing two radix-2 DIF Stockham stages (verified r3/r4 kernel):
// stage m (=4^s): j in [0,512), pm=floor(j/m)*m, a=src[j],b=src[j+512],c=src[j+1024],d=src[j+1536]
// t0=a+c t1=a-c t2=b+d t3=-i(b-d); dst[4pm+q + t*m] = W^(t*pm) * y_t,
// y0=t0+t2, y1=t1+t3, y2=t0-t2, y3=t1-t3. Final radix-2 (m=1024) has W^0 twiddles.
__device__ __forceinline__ float2* fft2048(float2* bufA, float2* bufB,
                                           const float2* __restrict__ twl) {
    float2* src = bufA;
    float2* dst = bufB;
    #pragma unroll
    for (int s = 0; s < 5; ++s) {
        int m = 1 << (2 * s);
        __syncthreads();
        #pragma unroll
        for (int jj = 0; jj < 2; ++jj) {
            int j  = (int)threadIdx.x + jj * 256;   // 0..511
            int pm = j & ~(m - 1);
            float2 w1 = twl[pm], w2 = twl[2 * pm], w3 = twl[3 * pm];
            float2 a = src[IDX(j)], b = src[IDX(j + 512)];
            float2 c = src[IDX(j + 1024)], d = src[IDX(j + 1536)];
            float t0x = a.x + c.x, t0y = a.y + c.y;
            float t1x = a.x - c.x, t1y = a.y - c.y;
            float t2x = b.x + d.x, t2y = b.y + d.y;
            float t3x = b.y - d.y, t3y = d.x - b.x;        // -i*(b-d)
            int base = 3 * pm + j;                          // = 4*pm + q
            dst[IDX(base)]         = make_float2(t0x + t2x, t0y + t2y);
            dst[IDX(base + m)]     = cmulf(w1, make_float2(t1x + t3x, t1y + t3y));
            dst[IDX(base + 2 * m)] = cmulf(w2, make_float2(t0x - t2x, t0y - t2y));
            dst[IDX(base + 3 * m)] = cmulf(w3, make_float2(t1x - t3x, t1y - t3y));
        }
        float2* t = src; src = dst; dst = t;
    }
    __syncthreads();
    #pragma unroll
    for (int jj = 0; jj < 4; ++jj) {
        int j = (int)threadIdx.x + jj * 256;               // 0..1023
        float2 a = src[IDX(j)], b = src[IDX(j + 1024)];
        dst[IDX(j)]        = make_float2(a.x + b.x, a.y + b.y);
        dst[IDX(j + 1024)] = make_float2(a.x - b.x, a.y - b.y);
    }
    { float2* t = src; src = dst; dst = t; }
    __syncthreads();
    return src;
}

// ---------------- pass 1: row FFTs (roll remap + apod), store kx<KXROWS ----------------
__global__ __launch_bounds__(256) void fft_rows(const float* __restrict__ img,
                                                const float* __restrict__ apod,
                                                const float2* __restrict__ twg,
                                                float2* __restrict__ R) {
    __shared__ float2 bufA[2176];
    __shared__ float2 bufB[2176];
    __shared__ float2 twl[TWN];
    int y = blockIdx.x, c = blockIdx.y;
    for (int t = threadIdx.x; t < TWN; t += 256) twl[t] = twg[t];
    float ay = apod[y];
    const float* row = img + ((size_t)c * NPIXD + y) * NPIXD;
    for (int n = threadIdx.x; n < GD; n += 256) {
        float v = 0.0f;
        if (n < 512)        v = row[n + 512]  * apod[n + 512];
        else if (n >= 1536) v = row[n - 1536] * apod[n - 1536];
        bufA[IDX(n)] = make_float2(v * ay, 0.0f);
    }
    float2* res = fft2048(bufA, bufB, twl);
    float2* outr = R + ((size_t)c * NPIXD + y) * RP;
    for (int kx = threadIdx.x; kx < KXROWS; kx += 256) outr[kx] = res[IDX(kx)];
}

// ---------------- transpose: R[c][y][kx] -> Fin[c][kx][y] ----------------
__global__ __launch_bounds__(256) void transpose_k(const float2* __restrict__ R,
                                                   float2* __restrict__ Fin) {
    __shared__ float2 tile[32][33];
    int c = blockIdx.z, kx0 = blockIdx.x * 32, y0 = blockIdx.y * 32;
    int tx = threadIdx.x;
    for (int i = threadIdx.y; i < 32; i += 8)
        if (kx0 + tx < KXROWS)
            tile[i][tx] = R[((size_t)c * NPIXD + (y0 + i)) * RP + kx0 + tx];
    __syncthreads();
    for (int i = threadIdx.y; i < 32; i += 8)
        if (kx0 + i < KXROWS)
            Fin[((size_t)c * KXROWS + (kx0 + i)) * FINP + (y0 + tx)] = tile[tx][i];
}

// ---------------- pass 2: col FFTs, y-packed store ----------------
__global__ __launch_bounds__(256) void fft_cols(const float2* __restrict__ Fin,
                                                float2* __restrict__ Fh,
                                                const float2* __restrict__ twg) {
    __shared__ float2 bufA[2176];
    __shared__ float2 bufB[2176];
    __shared__ float2 twl[TWN];
    int kx = blockIdx.x, c = blockIdx.y;
    for (int t = threadIdx.x; t < TWN; t += 256) twl[t] = twg[t];
    const float2* inr = Fin + ((size_t)c * KXROWS + kx) * FINP;
    for (int n = threadIdx.x; n < GD; n += 256) {
        float2 v = make_float2(0.0f, 0.0f);
        if (n < 512)        v = inr[n + 512];    // y = m+512
        else if (n >= 1536) v = inr[n - 1536];   // y = m-1536
        bufA[IDX(n)] = v;
    }
    float2* res = fft2048(bufA, bufB, twl);
    float2* outr = Fh + ((size_t)c * KXROWS + kx) * YPACK;
    for (int n = threadIdx.x; n < GD; n += 256) {
        if (n < 416)        outr[n]        = res[IDX(n)];
        else if (n >= 1632) outr[n - 1216] = res[IDX(n)];
    }
}

// ---------------- Kaiser-Bessel weights ----------------
__device__ __forceinline__ float i0f(float x) {
    float ax = fabsf(x);
    if (ax <= 3.75f) {
        float ts = ax / 3.75f; ts *= ts;
        return 1.0f + ts * (3.5156229f + ts * (3.0899424f + ts * (1.2067492f +
                     ts * (0.2659732f + ts * (0.0360768f + ts * 0.0045813f)))));
    } else {
        float t = 3.75f / ax;
        return expf(ax) / sqrtf(ax) *
               (0.39894228f + t * (0.01328592f + t * (0.00225319f + t * (-0.00157565f +
                t * (0.00916281f + t * (-0.02057706f + t * (0.02635537f +
                t * (-0.01647633f + t * 0.00392377f))))))));
    }
}

__device__ __forceinline__ float kbwf(float dist) {
    float r = dist * (2.0f / 6.0f);
    float s = 1.0f - r * r;
    if (s <= 0.0f) return 0.0f;
    return i0f(BETA_F * sqrtf(s)) * (1.0f / 6.0f);
}

// ---------------- gather: 64 vis x 4 ch per block, cooperative weights in LDS ----------
// smem row (stride 37 words): [0..5] wx f32, [6..11] wy f32, [12..17] kx i32,
// [18..23] cj i32, [24..29] py i32, [30..35] pyn i32
#define WSTR 37
__global__ __launch_bounds__(256) void gather2(const float* __restrict__ uu,
                                               const float* __restrict__ vv,
                                               const float2* __restrict__ Fh,
                                               float* __restrict__ out,
                                               int out_elems, int complexOut) {
    __shared__ float smem[64 * WSTR];
    int tid = threadIdx.x;
    int v = tid & 63, p = tid >> 6;
    int gv = blockIdx.x * 64 + v;          // NVISD = 3125*64 exactly
    {
        float t = (p < 2 ? uu[gv] : vv[gv]) * SCALE_F;
        float f = floorf(t);
        float* rowm = smem + v * WSTR;
        int*   rowi = (int*)rowm;
        #pragma unroll
        for (int it = 0; it < 3; ++it) {
            int i = p * 3 + it;                       // 0..11
            int o = (i < 6 ? i : i - 6) - 2;          // -2..3
            float w = kbwf(t - f - (float)o);
            int ii = (int)f + o;
            if (i < 6) {
                rowm[i] = w;
                int ix = ii & (GD - 1);
                int cj = (ix > 1024) ? 1 : 0;
                int kx = cj ? (GD - ix) : ix;
                rowi[12 + i] = min(kx, KXROWS - 1);
                rowi[18 + i] = cj;
            } else {
                rowm[i] = w;
                int iy  = ii & (GD - 1);
                int py  = (iy < 1024) ? iy : iy - 1216;
                int iyn = (GD - iy) & (GD - 1);
                int pyn = (iyn < 1024) ? iyn : iyn - 1216;
                rowi[24 + (i - 6)] = min(max(py, 0), YPACK - 1);
                rowi[30 + (i - 6)] = min(max(pyn, 0), YPACK - 1);
            }
        }
    }
    __syncthreads();
    int c = p;
    const float* rowm = smem + v * WSTR;
    const int*   rowi = (const int*)rowm;
    float wxr[6], wyr[6];
    int kxr[6], cjr[6], pyr[6], pynr[6];
    #pragma unroll
    for (int i = 0; i < 6; ++i) {
        wxr[i]  = rowm[i];
        wyr[i]  = rowm[6 + i];
        kxr[i]  = rowi[12 + i];
        cjr[i]  = rowi[18 + i];
        pyr[i]  = rowi[24 + i];
        pynr[i] = rowi[30 + i];
    }
    const float2* FhC = Fh + (size_t)c * KXROWS * YPACK;
    float sx = 0.0f, sy = 0.0f;
    #pragma unroll
    for (int b = 0; b < 6; ++b) {
        const float2* rp = FhC + (size_t)kxr[b] * YPACK;
        float wxb = wxr[b];
        bool cj = cjr[b] != 0;
        #pragma unroll
        for (int a = 0; a < 6; ++a) {
            int idx = cj ? pynr[a] : pyr[a];
            float2 z = rp[idx];
            float w = wxb * wyr[a];
            sx = fmaf(w, z.x, sx);
            if (complexOut) sy = fmaf(cj ? -w : w, z.y, sy);
        }
    }
    size_t oidx = (size_t)c * NVISD + gv;
    if (complexOut) {
        if (2 * oidx + 1 < (size_t)out_elems) { out[2 * oidx] = sx; out[2 * oidx + 1] = sy; }
    } else {
        if (oidx < (size_t)out_elems) out[oidx] = sx;
    }
}

extern "C" void kernel_launch(void* const* d_in, const int* in_sizes, int n_in,
                              void* d_out, int out_size, void* d_ws, size_t ws_size,
                              hipStream_t stream) {
    (void)in_sizes; (void)n_in;
    const float* img = (const float*)d_in[0];
    const float* uu  = (const float*)d_in[1];
    const float* vv  = (const float*)d_in[2];

    const size_t apodBytes = 4096;
    const size_t twBytes   = 16384;                                        // TWN*8 = 12KB, pad
    const size_t rBytes    = (size_t)NCHAND * NPIXD * RP * sizeof(float2); // 13.4 MB
    const size_t finBytes  = (size_t)NCHAND * KXROWS * FINP * sizeof(float2); // 13.4 MB
    const size_t fhBytes   = (size_t)NCHAND * KXROWS * YPACK * sizeof(float2); // 10.9 MB
    const size_t need = apodBytes + twBytes + rBytes + finBytes + fhBytes; // ~37.7 MB

    char* ws = (char*)d_ws;
    float*  apod = (float*)ws;
    float2* twg  = (float2*)(ws + apodBytes);
    float2* R    = (float2*)(ws + apodBytes + twBytes);
    float2* Fin  = (float2*)(ws + apodBytes + twBytes + rBytes);
    float2* Fh   = (float2*)(ws + apodBytes + twBytes + rBytes + finBytes);

    if (ws_size < need) return;  // diagnostic guard (ws >= 67MB established r3)

    int complexOut = (out_size >= 2 * NCHAND * NVISD) ? 1 : 0;

    apod_kernel<<<dim3(4), dim3(256), 0, stream>>>(apod);
    twiddle_kernel<<<dim3(6), dim3(256), 0, stream>>>(twg);
    fft_rows<<<dim3(NPIXD, NCHAND), dim3(256), 0, stream>>>(img, apod, twg, R);
    transpose_k<<<dim3((KXROWS + 31) / 32, NPIXD / 32, NCHAND), dim3(32, 8), 0, stream>>>(R, Fin);
    fft_cols<<<dim3(KXROWS, NCHAND), dim3(256), 0, stream>>>(Fin, Fh, twg);
    gather2<<<dim3(NVISD / 64), dim3(256), 0, stream>>>(
        uu, vv, Fh, (float*)d_out, out_size, complexOut);
}